// Round 5
// baseline (396.096 us; speedup 1.0000x reference)
//
#include <hip/hip_runtime.h>
#include <math.h>

// Problem constants
#define BB 8
#define KK 4
#define LL 1024
#define DD 512
#define HD 64
#define D3 1536
#define MM (BB*LL*KK)   // 32768 rows for per-state GEMMs
#define BL (BB*LL)      // 8192 (b,l) positions
#define SCALE 0.125f
#define EPSF 1e-8f
#define LN_EPSF 1e-5f

typedef _Float16 hfrag __attribute__((ext_vector_type(8)));
typedef float f32x4 __attribute__((ext_vector_type(4)));

__device__ __forceinline__ unsigned short f2h(float f) {
    _Float16 h = (_Float16)f;
    unsigned short u; __builtin_memcpy(&u, &h, 2); return u;
}
__device__ __forceinline__ float h2f(unsigned short u) {
    _Float16 h; __builtin_memcpy(&h, &u, 2); return (float)h;
}

__device__ __forceinline__ void glds16(const unsigned short* g, unsigned short* l) {
    __builtin_amdgcn_global_load_lds(
        (const __attribute__((address_space(1))) void*)g,
        (__attribute__((address_space(3))) void*)l, 16, 0, 0);
}

// Inline nsw: normalized state weight for (b,k) from sw/pres (32 elems, L2-hot)
__device__ __forceinline__ void nsw_compute(const float* sw, const int* pres,
                                            int b, float* nswv) {
    float w[KK], pr[KK]; float denom = 0.f, ps = 0.f;
    #pragma unroll
    for (int k = 0; k < KK; ++k) {
        pr[k] = pres[b*KK + k] ? 1.f : 0.f;
        w[k]  = sw[b*KK + k] * pr[k];
        denom += w[k]; ps += pr[k];
    }
    #pragma unroll
    for (int k = 0; k < KK; ++k)
        nswv[k] = (denom > EPSF) ? w[k] / fmaxf(denom, EPSF)
                                 : pr[k] / fmaxf(ps, 1.f);
}

// ---------------------------------------------------------------------------
// Fused fp32 -> fp16 weight conversion (Wq|Wk|Wv|Wo|Wg1|Wg2 concatenated)
#define WSZ 262144          // 512*512
#define OG1 1048576         // start of Wg1 (512*1536)
#define OG2 1835008         // start of Wg2
#define WTOT 2097152
__global__ __launch_bounds__(256) void cvt_weights(
        const float* __restrict__ Wq, const float* __restrict__ Wk,
        const float* __restrict__ Wv, const float* __restrict__ Wo,
        const float* __restrict__ Wg1, const float* __restrict__ Wg2,
        unsigned short* __restrict__ dst) {
    int t = blockIdx.x * 256 + threadIdx.x;   // one float4 per thread
    int e = t * 4;
    const float* src; int off;
    if      (e < WSZ)    { src = Wq;  off = e; }
    else if (e < 2*WSZ)  { src = Wk;  off = e - WSZ; }
    else if (e < 3*WSZ)  { src = Wv;  off = e - 2*WSZ; }
    else if (e < OG1)    { src = Wo;  off = e - 3*WSZ; }
    else if (e < OG2)    { src = Wg1; off = e - OG1; }
    else                 { src = Wg2; off = e - OG2; }
    float4 v = *(const float4*)(src + off);
    ushort4 o;
    o.x = f2h(v.x); o.y = f2h(v.y); o.z = f2h(v.z); o.w = f2h(v.w);
    *(ushort4*)(dst + e) = o;
}

// ---------------------------------------------------------------------------
// Build x (fp16) + weighted_mean/max_feat (fp32, exact) + rowmask + f_nsw.
__global__ __launch_bounds__(256) void buildx_kernel(
        const float* __restrict__ SR, const int* __restrict__ residue,
        const int* __restrict__ pres, const int* __restrict__ roles,
        const float* __restrict__ role_emb, const float* __restrict__ sw,
        unsigned short* __restrict__ Xh, float* __restrict__ rowmask,
        float* __restrict__ out_wm, float* __restrict__ out_mx,
        float* __restrict__ f_nsw) {
    int t  = blockIdx.x * 256 + threadIdx.x;
    int bl = t >> 7;
    int d4 = (t & 127) << 2;
    int b  = bl >> 10, l = bl & 1023;
    float nswv[KK];
    nsw_compute(sw, pres, b, nswv);
    float mk[KK], swr[KK];
    float ssum = 0.f, many = 0.f;
    #pragma unroll
    for (int k = 0; k < KK; ++k) {
        int bk = b*KK + k;
        bool valid = (residue[(size_t)bk*LL + l] != 0) && (pres[bk] != 0);
        mk[k]  = valid ? 1.f : 0.f;
        swr[k] = nswv[k] * mk[k];
        ssum += swr[k]; many += mk[k];
    }
    float inv = 1.f / fmaxf(ssum, EPSF);
    bool hasany = many > 0.5f;
    float wmx = 0.f, wmy = 0.f, wmz = 0.f, wmw = 0.f;
    float mxx = -1e9f, mxy = -1e9f, mxz = -1e9f, mxw = -1e9f;
    #pragma unroll
    for (int k = 0; k < KK; ++k) {
        int bk = b*KK + k;
        int role = roles[bk]; if (role < 0) role = 0;
        float4 sr = *(const float4*)(SR + ((size_t)bk*LL + l)*DD + d4);
        float4 re = *(const float4*)(role_emb + (size_t)role*DD + d4);
        float xx = (sr.x + re.x)*mk[k], xy = (sr.y + re.y)*mk[k];
        float xz = (sr.z + re.z)*mk[k], xw = (sr.w + re.w)*mk[k];
        ushort4 xs; xs.x = f2h(xx); xs.y = f2h(xy); xs.z = f2h(xz); xs.w = f2h(xw);
        *(ushort4*)(Xh + (size_t)(bl*KK + k)*DD + d4) = xs;
        float s = swr[k]*inv;
        wmx = fmaf(xx, s, wmx); wmy = fmaf(xy, s, wmy);
        wmz = fmaf(xz, s, wmz); wmw = fmaf(xw, s, wmw);
        if (mk[k] > 0.5f) {
            mxx = fmaxf(mxx, xx); mxy = fmaxf(mxy, xy);
            mxz = fmaxf(mxz, xz); mxw = fmaxf(mxw, xw);
        }
    }
    if (!hasany) { mxx = mxy = mxz = mxw = 0.f; }
    float4 wmv; wmv.x = wmx; wmv.y = wmy; wmv.z = wmz; wmv.w = wmw;
    float4 mxv; mxv.x = mxx; mxv.y = mxy; mxv.z = mxz; mxv.w = mxw;
    *(float4*)(out_wm + (size_t)bl*DD + d4) = wmv;
    *(float4*)(out_mx + (size_t)bl*DD + d4) = mxv;
    if (d4 == 0) {
        #pragma unroll
        for (int k = 0; k < KK; ++k) rowmask[bl*KK + k] = mk[k];
    }
    if (blockIdx.x == 0 && threadIdx.x < BB*KK) {
        int bb = threadIdx.x >> 2, kk2 = threadIdx.x & 3;
        float nv[KK];
        nsw_compute(sw, pres, bb, nv);
        f_nsw[threadIdx.x] = nv[kk2];
    }
}

// ---------------------------------------------------------------------------
// MFMA GEMM: C[M,N] = A[M,K] @ W[N,K]^T, fp16 in, fp32 accum.
// TM in {128, 64, 32} tile rows; 128 tile cols; BK=32; 4 waves (2x2).
//   TM=128: wave does 64x64 (4x4 frags), LDS 16 KB.
//   TM=64 : wave does 32x64 (2x4 frags), LDS 12 KB.
//   TM=32 : wave does 16x64 (1x4 frags), LDS 10 KB; A staged by waves 0-1.
// EPI: 0=none, 1=*rowmask[m], 2=bias+gelu(exact), 3=bias+sigmoid
// OUTH: 1 = fp16 output, 0 = fp32 output
// QKVR: 1 = route output by 512-column segment into 3 consecutive (M,512)
//        buffers starting at Cv (segments never straddle a 128-col block).
template<int TM, int EPI, int OUTH, int QKVR>
__global__ __launch_bounds__(256) void gemm_mfma(
        const unsigned short* __restrict__ A, const unsigned short* __restrict__ W,
        void* __restrict__ Cv, int M, int N, int Kd,
        const float* __restrict__ bias, const float* __restrict__ rowmask) {
    constexpr int FI = TM / 32;          // M-frags per wave: 4, 2, or 1
    __shared__ __align__(16) unsigned short As[TM*32];
    __shared__ __align__(16) unsigned short Bs[128*32];
    const int tid  = threadIdx.x;
    const int wave = tid >> 6, lane = tid & 63;
    const int m0 = blockIdx.y * TM, n0 = blockIdx.x * 128;
    const int srow = lane >> 2;          // 0..15
    const int scol = (lane & 3) << 3;    // 0,8,16,24
    const int arow = (TM == 128) ? (wave*32 + srow)
                   : (TM == 64)  ? (wave*16 + srow)
                   :               ((wave & 1)*16 + srow);
    const bool astage = (TM >= 64) || (wave < 2);
    const unsigned short* Ag0 = A + (size_t)(m0 + arow) * Kd + scol;
    const unsigned short* Ag1 = Ag0 + (size_t)16 * Kd;      // TM==128 only
    unsigned short* Al0 = As + arow*32 + scol;
    unsigned short* Al1 = Al0 + 16*32;
    const unsigned short* Wp0 = W + (size_t)(n0 + wave*32 + srow) * Kd + scol;
    const unsigned short* Wp1 = Wp0 + (size_t)16 * Kd;
    unsigned short* Bl0 = Bs + (wave*32 + srow)*32 + scol;
    unsigned short* Bl1 = Bl0 + 16*32;
    const int wr = (wave >> 1) * (TM/2);
    const int wc = (wave & 1) * 64;
    const int fr = lane & 15;
    const int fq = (lane >> 4) * 8;
    f32x4 acc[FI][4] = {};
    for (int k0 = 0; k0 < Kd; k0 += 32) {
        if (astage)    glds16(Ag0 + k0, Al0);
        if (TM == 128) glds16(Ag1 + k0, Al1);
        glds16(Wp0 + k0, Bl0);
        glds16(Wp1 + k0, Bl1);
        __syncthreads();
        hfrag af[FI], bf[4];
        #pragma unroll
        for (int i = 0; i < FI; ++i)
            af[i] = *(const hfrag*)(As + (wr + i*16 + fr)*32 + fq);
        #pragma unroll
        for (int j = 0; j < 4; ++j)
            bf[j] = *(const hfrag*)(Bs + (wc + j*16 + fr)*32 + fq);
        #pragma unroll
        for (int i = 0; i < FI; ++i)
            #pragma unroll
            for (int j = 0; j < 4; ++j)
                acc[i][j] = __builtin_amdgcn_mfma_f32_16x16x32_f16(af[i], bf[j], acc[i][j], 0, 0, 0);
        __syncthreads();
    }
    // Output routing for fused QKV
    unsigned short* Ch = (unsigned short*)Cv;
    int Nout = N, colbase = n0;
    if (QKVR) {
        const int seg = n0 >> 9;
        Ch = (unsigned short*)Cv + (size_t)seg * M * 512;
        Nout = 512;
        colbase = n0 - (seg << 9);
    }
    #pragma unroll
    for (int i = 0; i < FI; ++i) {
        const int row = m0 + wr + i*16 + (lane >> 4)*4;
        float rm[4];
        if (EPI == 1) {
            #pragma unroll
            for (int r = 0; r < 4; ++r) rm[r] = rowmask[row + r];
        }
        #pragma unroll
        for (int j = 0; j < 4; ++j) {
            const int col = colbase + wc + j*16 + (lane & 15);
            float bv = (EPI == 2 || EPI == 3) ? bias[col] : 0.f;
            #pragma unroll
            for (int r = 0; r < 4; ++r) {
                float v = acc[i][j][r];
                if (EPI == 1) v *= rm[r];
                if (EPI == 2) { v += bv; v = 0.5f * v * (1.f + erff(v * 0.70710678118654752f)); }
                if (EPI == 3) { v += bv; v = 1.f / (1.f + expf(-v)); }
                if (OUTH) Ch[(size_t)(row + r) * Nout + col] = f2h(v);
                else      ((float*)Cv)[(size_t)(row + r) * Nout + col] = v;
            }
        }
    }
}

// ---------------------------------------------------------------------------
// Per-(b,l) attention over K=4 states, fp16 q/k/v, fp32 math in LDS.
__global__ __launch_bounds__(256) void attn_kernel(
        unsigned short* Qb /* in: q, out: attn_out */,
        const unsigned short* __restrict__ Kb, const unsigned short* __restrict__ Vb,
        const float* __restrict__ sw, const int* __restrict__ pres,
        const float* __restrict__ rowmask,
        float* __restrict__ attn_mean_out) {
    __shared__ float qs[KK][DD];
    __shared__ float ksm[KK][DD];
    __shared__ float vs[KK][DD];
    __shared__ float att[128];           // [h*16 + i*4 + j]
    __shared__ float lw[KK], mk[KK];
    int bl = blockIdx.x, b = bl >> 10, mb = bl * KK;
    int tid = threadIdx.x;
    const ushort4* q4 = (const ushort4*)(Qb + (size_t)mb*DD);
    const ushort4* k4 = (const ushort4*)(Kb + (size_t)mb*DD);
    const ushort4* v4 = (const ushort4*)(Vb + (size_t)mb*DD);
    #pragma unroll
    for (int p = 0; p < 2; ++p) {
        int idx = p*256 + tid;
        int k = idx >> 7, dd = (idx & 127) << 2;
        ushort4 a = q4[idx];
        qs[k][dd] = h2f(a.x); qs[k][dd+1] = h2f(a.y); qs[k][dd+2] = h2f(a.z); qs[k][dd+3] = h2f(a.w);
        ushort4 c = k4[idx];
        ksm[k][dd] = h2f(c.x); ksm[k][dd+1] = h2f(c.y); ksm[k][dd+2] = h2f(c.z); ksm[k][dd+3] = h2f(c.w);
        ushort4 e = v4[idx];
        vs[k][dd] = h2f(e.x); vs[k][dd+1] = h2f(e.y); vs[k][dd+2] = h2f(e.z); vs[k][dd+3] = h2f(e.w);
    }
    if (tid < KK) {
        float nv[KK];
        nsw_compute(sw, pres, b, nv);
        lw[tid] = logf(fmaxf(nv[tid], EPSF));
        mk[tid] = rowmask[mb + tid];
    }
    __syncthreads();
    if (tid < 128) {
        int h = tid >> 4, i = (tid >> 2) & 3, j = tid & 3;
        float s = 0.f;
        #pragma unroll 16
        for (int d = 0; d < HD; ++d) s = fmaf(qs[i][h*HD + d], ksm[j][h*HD + d], s);
        float lg = s * SCALE + lw[j];
        att[tid] = (mk[j] > 0.5f) ? lg : -INFINITY;
    }
    __syncthreads();
    if (tid < 32) {
        int base = tid * 4;
        float l0 = att[base], l1 = att[base+1], l2 = att[base+2], l3 = att[base+3];
        float m = fmaxf(fmaxf(l0, l1), fmaxf(l2, l3));
        if (m == -INFINITY) {
            att[base] = att[base+1] = att[base+2] = att[base+3] = 0.f;
        } else {
            float e0 = expf(l0 - m), e1 = expf(l1 - m), e2 = expf(l2 - m), e3 = expf(l3 - m);
            float inv = 1.f / (e0 + e1 + e2 + e3);
            att[base] = e0*inv; att[base+1] = e1*inv; att[base+2] = e2*inv; att[base+3] = e3*inv;
        }
    }
    __syncthreads();
    if (tid < KK) {
        float s = 0.f;
        for (int hi = 0; hi < 32; ++hi) s += att[hi*4 + tid];
        attn_mean_out[(size_t)bl*KK + tid] = s * (1.f/32.f);
    }
    float outv[8];
    #pragma unroll
    for (int p = 0; p < 8; ++p) {
        int idx = p*256 + tid;
        int i = idx >> 9, dc = idx & 511, h = dc >> 6;
        float s = 0.f;
        #pragma unroll
        for (int j = 0; j < KK; ++j) s = fmaf(att[h*16 + i*4 + j], vs[j][dc], s);
        outv[p] = s;
    }
    #pragma unroll
    for (int p = 0; p < 8; ++p) {
        int idx = p*256 + tid;
        int i = idx >> 9, dc = idx & 511;
        Qb[(size_t)(mb+i)*DD + dc] = f2h(outv[p]);
    }
}

// ---------------------------------------------------------------------------
__device__ __forceinline__ void block_reduce2(float& a, float& b, float* lds) {
    #pragma unroll
    for (int o = 32; o > 0; o >>= 1) {
        a += __shfl_down(a, o, 64);
        b += __shfl_down(b, o, 64);
    }
    int wave = threadIdx.x >> 6, lane = threadIdx.x & 63;
    if (lane == 0) { lds[wave*2] = a; lds[wave*2+1] = b; }
    __syncthreads();
    if (threadIdx.x == 0) {
        float sa = 0.f, sb = 0.f;
        for (int w = 0; w < 4; ++w) { sa += lds[2*w]; sb += lds[2*w+1]; }
        lds[0] = sa; lds[1] = sb;
    }
    __syncthreads();
    a = lds[0]; b = lds[1];
    __syncthreads();
}

// attn_pooled + LN1(gate_in) -> Hin (fp16); wm/mx read back from d_out (fp32).
__global__ __launch_bounds__(256) void pool_kernel(
        const unsigned short* __restrict__ AOP,
        const float* __restrict__ sw, const int* __restrict__ pres,
        const float* __restrict__ rowmask,
        const float* __restrict__ in_wm, const float* __restrict__ in_mx,
        const float* __restrict__ ln1_g, const float* __restrict__ ln1_b,
        float* __restrict__ out_ap, unsigned short* __restrict__ hin) {
    __shared__ float red[16];
    int bl = blockIdx.x, b = bl >> 10, mb = bl * KK;
    int tid = threadIdx.x;
    float nswv[KK];
    nsw_compute(sw, pres, b, nswv);
    float swr[KK]; float ssum = 0.f;
    #pragma unroll
    for (int k = 0; k < KK; ++k) {
        swr[k] = nswv[k] * rowmask[mb + k];
        ssum += swr[k];
    }
    float inv = 1.f / fmaxf(ssum, EPSF);
    #pragma unroll
    for (int k = 0; k < KK; ++k) swr[k] *= inv;
    float apv[2], wmv[2], mxv[2];
    float lsum = 0.f, lsq = 0.f;
    #pragma unroll
    for (int it = 0; it < 2; ++it) {
        int d = tid + it*256;
        float ap = 0.f;
        #pragma unroll
        for (int k = 0; k < KK; ++k)
            ap = fmaf(h2f(AOP[(size_t)(mb+k)*DD + d]), swr[k], ap);
        float wm = in_wm[(size_t)bl*DD + d];
        float mx = in_mx[(size_t)bl*DD + d];
        apv[it] = ap; wmv[it] = wm; mxv[it] = mx;
        lsum += ap + wm + mx;
        lsq  += ap*ap + wm*wm + mx*mx;
    }
    block_reduce2(lsum, lsq, red);
    float mu = lsum * (1.f/(float)D3);
    float var = lsq * (1.f/(float)D3) - mu*mu;
    float rstd = rsqrtf(var + LN_EPSF);
    #pragma unroll
    for (int it = 0; it < 2; ++it) {
        int d = tid + it*256;
        out_ap[(size_t)bl*DD + d] = apv[it];
        hin[(size_t)bl*D3 + d]        = f2h((apv[it]-mu)*rstd*ln1_g[d]        + ln1_b[d]);
        hin[(size_t)bl*D3 + 512 + d]  = f2h((wmv[it]-mu)*rstd*ln1_g[512 + d]  + ln1_b[512 + d]);
        hin[(size_t)bl*D3 + 1024 + d] = f2h((mxv[it]-mu)*rstd*ln1_g[1024 + d] + ln1_b[1024 + d]);
    }
}

// ---------------------------------------------------------------------------
__global__ __launch_bounds__(256) void final_kernel(
        const float* __restrict__ out_ap, const float* __restrict__ out_wm,
        const float* __restrict__ out_mx, const float* __restrict__ gate,
        const float* __restrict__ norm_g, const float* __restrict__ norm_b,
        float* __restrict__ fused) {
    __shared__ float red[16];
    int bl = blockIdx.x;
    int tid = threadIdx.x;
    float pre[2];
    float lsum = 0.f, lsq = 0.f;
    #pragma unroll
    for (int it = 0; it < 2; ++it) {
        int d = tid + it*256;
        float ap = out_ap[(size_t)bl*DD + d];
        float wm = out_wm[(size_t)bl*DD + d];
        float mx = out_mx[(size_t)bl*DD + d];
        float g  = gate[(size_t)bl*DD + d];
        float fb = 0.5f * (ap + wm);
        float p = g*fb + (1.f-g)*mx + wm;
        pre[it] = p;
        lsum += p; lsq += p*p;
    }
    block_reduce2(lsum, lsq, red);
    float mu = lsum * (1.f/(float)DD);
    float var = lsq * (1.f/(float)DD) - mu*mu;
    float rstd = rsqrtf(var + LN_EPSF);
    #pragma unroll
    for (int it = 0; it < 2; ++it) {
        int d = tid + it*256;
        fused[(size_t)bl*DD + d] = (pre[it]-mu)*rstd*norm_g[d] + norm_b[d];
    }
}

// ---------------------------------------------------------------------------
extern "C" void kernel_launch(void* const* d_in, const int* in_sizes, int n_in,
                              void* d_out, int out_size, void* d_ws, size_t ws_size,
                              hipStream_t stream) {
    const float* SR      = (const float*)d_in[0];
    const int*   residue = (const int*)d_in[1];
    const float* sw      = (const float*)d_in[2];
    const int*   roles   = (const int*)d_in[3];
    const int*   pres    = (const int*)d_in[4];
    const float* role_emb= (const float*)d_in[5];
    const float* Wq      = (const float*)d_in[6];
    const float* Wk      = (const float*)d_in[7];
    const float* Wv      = (const float*)d_in[8];
    const float* Wo      = (const float*)d_in[9];
    const float* ln1_g   = (const float*)d_in[10];
    const float* ln1_b   = (const float*)d_in[11];
    const float* Wg1     = (const float*)d_in[12];
    const float* bg1     = (const float*)d_in[13];
    const float* Wg2     = (const float*)d_in[14];
    const float* bg2     = (const float*)d_in[15];
    const float* norm_g  = (const float*)d_in[16];
    const float* norm_b  = (const float*)d_in[17];

    float* out = (float*)d_out;
    const size_t BLD = (size_t)BL * DD;
    float* f_fused = out;
    float* f_ap    = out + BLD;
    float* f_wm    = out + 2*BLD;
    float* f_mx    = out + 3*BLD;
    float* f_am    = out + 4*BLD;
    float* f_nsw   = out + 4*BLD + (size_t)BL*KK;

    char* base = (char*)d_ws;
    const size_t MD2 = (size_t)MM * DD * 2;     // 32 MB per fp16 activation buffer
    unsigned short* Xh = (unsigned short*)(base);
    unsigned short* Qh = (unsigned short*)(base + MD2);       // Q|K|V contiguous:
    unsigned short* Kh = (unsigned short*)(base + 2*MD2);     //  QKV routing relies
    unsigned short* Vh = (unsigned short*)(base + 3*MD2);     //  on this layout
    float*          Gate = (float*)(base + 4*MD2);                     // 16 MB
    unsigned short* Wb = (unsigned short*)(base + 4*MD2 + (size_t)BL*DD*4);  // 4 MB
    float* rmask = (float*)(base + 4*MD2 + (size_t)BL*DD*4 + (size_t)WTOT*2);
    unsigned short* AOh  = Qh;   // attn_out (in-place over q)
    unsigned short* APh  = Kh;   // attn_out @ Wo^T
    unsigned short* Hin  = Vh;   // (B,L,1536) fp16
    unsigned short* Hbuf = Xh;   // gelu(h) (B,L,512) fp16
    const unsigned short* Wqkv = Wb;            // (1536, 512) = [Wq;Wk;Wv]
    const unsigned short* Woh  = Wb + 3*WSZ;
    const unsigned short* Wg1h = Wb + OG1;
    const unsigned short* Wg2h = Wb + OG2;

    dim3 blk(256);

    cvt_weights<<<WTOT/1024, blk, 0, stream>>>(Wq, Wk, Wv, Wo, Wg1, Wg2, Wb);
    buildx_kernel<<<(BL*128)/256, blk, 0, stream>>>(SR, residue, pres, roles, role_emb,
                                                    sw, Xh, rmask, f_wm, f_mx, f_nsw);

    // Fused QKV: C[32768,1536] routed into Qh/Kh/Vh.  Grid (12,256)=3072 blocks.
    gemm_mfma<128,0,1,1><<<dim3(12, MM/128), blk, 0, stream>>>(
        Xh, Wqkv, Qh, MM, 1536, DD, nullptr, nullptr);

    attn_kernel<<<BL, blk, 0, stream>>>(Qh, Kh, Vh, sw, pres, rmask, f_am);

    // Wo: TM=64 -> grid (4,512)=2048 blocks (8 blocks/CU).
    gemm_mfma<64,1,1,0><<<dim3(4, MM/64), blk, 0, stream>>>(
        AOh, Woh, APh, MM, DD, DD, nullptr, rmask);

    pool_kernel<<<BL, blk, 0, stream>>>(APh, sw, pres, rmask, f_wm, f_mx, ln1_g, ln1_b,
                                        f_ap, Hin);

    // MLP: TM=32 tiles -> 1024 blocks each (4 blocks/CU).
    gemm_mfma<32,2,1,0><<<dim3(4, BL/32), blk, 0, stream>>>(
        Hin, Wg1h, Hbuf, BL, DD, D3, bg1, nullptr);
    gemm_mfma<32,3,0,0><<<dim3(4, BL/32), blk, 0, stream>>>(
        Hbuf, Wg2h, Gate, BL, DD, DD, bg2, nullptr);

    final_kernel<<<BL, blk, 0, stream>>>(f_ap, f_wm, f_mx, Gate, norm_g, norm_b, f_fused);
}

// Round 6
// 385.024 us; speedup vs baseline: 1.0288x; 1.0288x over previous
//
#include <hip/hip_runtime.h>
#include <math.h>

// Problem constants
#define BB 8
#define KK 4
#define LL 1024
#define DD 512
#define HD 64
#define D3 1536
#define MM (BB*LL*KK)   // 32768 rows for per-state GEMMs
#define BL (BB*LL)      // 8192 (b,l) positions
#define SCALE 0.125f
#define EPSF 1e-8f
#define LN_EPSF 1e-5f

typedef _Float16 hfrag __attribute__((ext_vector_type(8)));
typedef float f32x4 __attribute__((ext_vector_type(4)));

__device__ __forceinline__ unsigned short f2h(float f) {
    _Float16 h = (_Float16)f;
    unsigned short u; __builtin_memcpy(&u, &h, 2); return u;
}
__device__ __forceinline__ float h2f(unsigned short u) {
    _Float16 h; __builtin_memcpy(&h, &u, 2); return (float)h;
}

__device__ __forceinline__ void glds16(const unsigned short* g, unsigned short* l) {
    __builtin_amdgcn_global_load_lds(
        (const __attribute__((address_space(1))) void*)g,
        (__attribute__((address_space(3))) void*)l, 16, 0, 0);
}

// Inline nsw: normalized state weight for (b,k) from sw/pres (32 elems, L2-hot)
__device__ __forceinline__ void nsw_compute(const float* sw, const int* pres,
                                            int b, float* nswv) {
    float w[KK], pr[KK]; float denom = 0.f, ps = 0.f;
    #pragma unroll
    for (int k = 0; k < KK; ++k) {
        pr[k] = pres[b*KK + k] ? 1.f : 0.f;
        w[k]  = sw[b*KK + k] * pr[k];
        denom += w[k]; ps += pr[k];
    }
    #pragma unroll
    for (int k = 0; k < KK; ++k)
        nswv[k] = (denom > EPSF) ? w[k] / fmaxf(denom, EPSF)
                                 : pr[k] / fmaxf(ps, 1.f);
}

// ---------------------------------------------------------------------------
// Fused fp32 -> fp16 weight conversion (Wq|Wk|Wv|Wo|Wg1|Wg2 concatenated)
#define WSZ 262144          // 512*512
#define OG1 1048576         // start of Wg1 (512*1536)
#define OG2 1835008         // start of Wg2
#define WTOT 2097152
__global__ __launch_bounds__(256) void cvt_weights(
        const float* __restrict__ Wq, const float* __restrict__ Wk,
        const float* __restrict__ Wv, const float* __restrict__ Wo,
        const float* __restrict__ Wg1, const float* __restrict__ Wg2,
        unsigned short* __restrict__ dst) {
    int t = blockIdx.x * 256 + threadIdx.x;   // one float4 per thread
    int e = t * 4;
    const float* src; int off;
    if      (e < WSZ)    { src = Wq;  off = e; }
    else if (e < 2*WSZ)  { src = Wk;  off = e - WSZ; }
    else if (e < 3*WSZ)  { src = Wv;  off = e - 2*WSZ; }
    else if (e < OG1)    { src = Wo;  off = e - 3*WSZ; }
    else if (e < OG2)    { src = Wg1; off = e - OG1; }
    else                 { src = Wg2; off = e - OG2; }
    float4 v = *(const float4*)(src + off);
    ushort4 o;
    o.x = f2h(v.x); o.y = f2h(v.y); o.z = f2h(v.z); o.w = f2h(v.w);
    *(ushort4*)(dst + e) = o;
}

// ---------------------------------------------------------------------------
// Build x (fp16) + weighted_mean/max_feat (fp32, exact) + rowmask + f_nsw.
__global__ __launch_bounds__(256) void buildx_kernel(
        const float* __restrict__ SR, const int* __restrict__ residue,
        const int* __restrict__ pres, const int* __restrict__ roles,
        const float* __restrict__ role_emb, const float* __restrict__ sw,
        unsigned short* __restrict__ Xh, float* __restrict__ rowmask,
        float* __restrict__ out_wm, float* __restrict__ out_mx,
        float* __restrict__ f_nsw) {
    int t  = blockIdx.x * 256 + threadIdx.x;
    int bl = t >> 7;
    int d4 = (t & 127) << 2;
    int b  = bl >> 10, l = bl & 1023;
    float nswv[KK];
    nsw_compute(sw, pres, b, nswv);
    float mk[KK], swr[KK];
    float ssum = 0.f, many = 0.f;
    #pragma unroll
    for (int k = 0; k < KK; ++k) {
        int bk = b*KK + k;
        bool valid = (residue[(size_t)bk*LL + l] != 0) && (pres[bk] != 0);
        mk[k]  = valid ? 1.f : 0.f;
        swr[k] = nswv[k] * mk[k];
        ssum += swr[k]; many += mk[k];
    }
    float inv = 1.f / fmaxf(ssum, EPSF);
    bool hasany = many > 0.5f;
    float wmx = 0.f, wmy = 0.f, wmz = 0.f, wmw = 0.f;
    float mxx = -1e9f, mxy = -1e9f, mxz = -1e9f, mxw = -1e9f;
    #pragma unroll
    for (int k = 0; k < KK; ++k) {
        int bk = b*KK + k;
        int role = roles[bk]; if (role < 0) role = 0;
        float4 sr = *(const float4*)(SR + ((size_t)bk*LL + l)*DD + d4);
        float4 re = *(const float4*)(role_emb + (size_t)role*DD + d4);
        float xx = (sr.x + re.x)*mk[k], xy = (sr.y + re.y)*mk[k];
        float xz = (sr.z + re.z)*mk[k], xw = (sr.w + re.w)*mk[k];
        ushort4 xs; xs.x = f2h(xx); xs.y = f2h(xy); xs.z = f2h(xz); xs.w = f2h(xw);
        *(ushort4*)(Xh + (size_t)(bl*KK + k)*DD + d4) = xs;
        float s = swr[k]*inv;
        wmx = fmaf(xx, s, wmx); wmy = fmaf(xy, s, wmy);
        wmz = fmaf(xz, s, wmz); wmw = fmaf(xw, s, wmw);
        if (mk[k] > 0.5f) {
            mxx = fmaxf(mxx, xx); mxy = fmaxf(mxy, xy);
            mxz = fmaxf(mxz, xz); mxw = fmaxf(mxw, xw);
        }
    }
    if (!hasany) { mxx = mxy = mxz = mxw = 0.f; }
    float4 wmv; wmv.x = wmx; wmv.y = wmy; wmv.z = wmz; wmv.w = wmw;
    float4 mxv; mxv.x = mxx; mxv.y = mxy; mxv.z = mxz; mxv.w = mxw;
    *(float4*)(out_wm + (size_t)bl*DD + d4) = wmv;
    *(float4*)(out_mx + (size_t)bl*DD + d4) = mxv;
    if (d4 == 0) {
        #pragma unroll
        for (int k = 0; k < KK; ++k) rowmask[bl*KK + k] = mk[k];
    }
    if (blockIdx.x == 0 && threadIdx.x < BB*KK) {
        int bb = threadIdx.x >> 2, kk2 = threadIdx.x & 3;
        float nv[KK];
        nsw_compute(sw, pres, bb, nv);
        f_nsw[threadIdx.x] = nv[kk2];
    }
}

// ---------------------------------------------------------------------------
// MFMA GEMM: C[M,N] = A[M,K] @ W[N,K]^T, fp16 in, fp32 accum.
// TM in {128, 64, 32} tile rows; 128 tile cols; BK=32; 4 waves (2x2).
// EPI: 0=none, 2=bias+gelu(exact)
// OUTH: 1 = fp16 output
// QKVR: route output by 512-col segment into 3 consecutive (M,512) buffers.
// SWZ : 1 = flat-grid XCD swizzle (grid.x = total blocks; xcd = id&7 gets a
//        contiguous band of 32 m-blocks with n fastest -> A tiles L2-resident).
template<int TM, int EPI, int OUTH, int QKVR, int SWZ>
__global__ __launch_bounds__(256) void gemm_mfma(
        const unsigned short* __restrict__ A, const unsigned short* __restrict__ W,
        void* __restrict__ Cv, int M, int N, int Kd,
        const float* __restrict__ bias, const float* __restrict__ rowmask) {
    constexpr int FI = TM / 32;          // M-frags per wave: 4, 2, or 1
    __shared__ __align__(16) unsigned short As[TM*32];
    __shared__ __align__(16) unsigned short Bs[128*32];
    const int tid  = threadIdx.x;
    const int wave = tid >> 6, lane = tid & 63;
    int m0, n0;
    if (SWZ) {
        int id = blockIdx.x;
        int c = id & 7, j = id >> 3;
        int mloc = j / 12;
        m0 = (c*32 + mloc) * TM;
        n0 = (j - mloc*12) * 128;
    } else {
        m0 = blockIdx.y * TM; n0 = blockIdx.x * 128;
    }
    const int srow = lane >> 2;          // 0..15
    const int scol = (lane & 3) << 3;    // 0,8,16,24
    const int arow = (TM == 128) ? (wave*32 + srow)
                   : (TM == 64)  ? (wave*16 + srow)
                   :               ((wave & 1)*16 + srow);
    const bool astage = (TM >= 64) || (wave < 2);
    const unsigned short* Ag0 = A + (size_t)(m0 + arow) * Kd + scol;
    const unsigned short* Ag1 = Ag0 + (size_t)16 * Kd;      // TM==128 only
    unsigned short* Al0 = As + arow*32 + scol;
    unsigned short* Al1 = Al0 + 16*32;
    const unsigned short* Wp0 = W + (size_t)(n0 + wave*32 + srow) * Kd + scol;
    const unsigned short* Wp1 = Wp0 + (size_t)16 * Kd;
    unsigned short* Bl0 = Bs + (wave*32 + srow)*32 + scol;
    unsigned short* Bl1 = Bl0 + 16*32;
    const int wr = (wave >> 1) * (TM/2);
    const int wc = (wave & 1) * 64;
    const int fr = lane & 15;
    const int fq = (lane >> 4) * 8;
    f32x4 acc[FI][4] = {};
    for (int k0 = 0; k0 < Kd; k0 += 32) {
        if (astage)    glds16(Ag0 + k0, Al0);
        if (TM == 128) glds16(Ag1 + k0, Al1);
        glds16(Wp0 + k0, Bl0);
        glds16(Wp1 + k0, Bl1);
        __syncthreads();
        hfrag af[FI], bf[4];
        #pragma unroll
        for (int i = 0; i < FI; ++i)
            af[i] = *(const hfrag*)(As + (wr + i*16 + fr)*32 + fq);
        #pragma unroll
        for (int j = 0; j < 4; ++j)
            bf[j] = *(const hfrag*)(Bs + (wc + j*16 + fr)*32 + fq);
        #pragma unroll
        for (int i = 0; i < FI; ++i)
            #pragma unroll
            for (int j = 0; j < 4; ++j)
                acc[i][j] = __builtin_amdgcn_mfma_f32_16x16x32_f16(af[i], bf[j], acc[i][j], 0, 0, 0);
        __syncthreads();
    }
    // Output routing for fused QKV
    unsigned short* Ch = (unsigned short*)Cv;
    int Nout = N, colbase = n0;
    if (QKVR) {
        const int seg = n0 >> 9;
        Ch = (unsigned short*)Cv + (size_t)seg * M * 512;
        Nout = 512;
        colbase = n0 - (seg << 9);
    }
    #pragma unroll
    for (int i = 0; i < FI; ++i) {
        const int row = m0 + wr + i*16 + (lane >> 4)*4;
        #pragma unroll
        for (int j = 0; j < 4; ++j) {
            const int col = colbase + wc + j*16 + (lane & 15);
            float bv = (EPI == 2) ? bias[col] : 0.f;
            #pragma unroll
            for (int r = 0; r < 4; ++r) {
                float v = acc[i][j][r];
                if (EPI == 2) { v += bv; v = 0.5f * v * (1.f + erff(v * 0.70710678118654752f)); }
                if (OUTH) Ch[(size_t)(row + r) * Nout + col] = f2h(v);
                else      ((float*)Cv)[(size_t)(row + r) * Nout + col] = v;
            }
        }
    }
}

// ---------------------------------------------------------------------------
// Fused Wo-projection + pooling + LN1:  per block 32 A-rows (= 8 bl) x all
// 512 cols.  C/D quad layout => lane's 4 acc regs (r) = the 4 k-states of one
// bl, so attn_pooled = per-lane dot with swr (mask absorbed: swr[k]=0 when
// invalid, matching reference attn_out*valid then swr-pool).
__global__ __launch_bounds__(256) void wo_pool_kernel(
        const unsigned short* __restrict__ A,   // attn_out (MM,512) fp16
        const unsigned short* __restrict__ W,   // Wo (512,512) fp16
        const float* __restrict__ sw, const int* __restrict__ pres,
        const float* __restrict__ rmask,
        const float* __restrict__ in_wm, const float* __restrict__ in_mx,
        const float* __restrict__ ln1_g, const float* __restrict__ ln1_b,
        float* __restrict__ out_ap, unsigned short* __restrict__ hin) {
    __shared__ __align__(16) unsigned short As[32*32];
    __shared__ __align__(16) unsigned short Bs[512*32];   // phase2: fp32 ap[8][512]
    const int tid = threadIdx.x, wave = tid >> 6, lane = tid & 63;
    const int m0 = blockIdx.x * 32;
    const int srow = lane >> 2, scol = (lane & 3) << 3;
    const unsigned short* Ag = A + (size_t)(m0 + wave*16 + srow)*512 + scol;
    unsigned short* Al = As + (wave*16 + srow)*32 + scol;
    const int brow = wave*128 + srow;
    const unsigned short* Wg = W + (size_t)brow*512 + scol;
    unsigned short* Blb = Bs + brow*32 + scol;
    const int q = lane >> 4, frl = lane & 15;
    const int fq = q * 8;
    f32x4 acc[2][8] = {};
    for (int k0 = 0; k0 < 512; k0 += 32) {
        if (wave < 2) glds16(Ag + k0, Al);
        #pragma unroll
        for (int i = 0; i < 8; ++i)
            glds16(Wg + (size_t)i*16*512 + k0, Blb + i*16*32);
        __syncthreads();
        hfrag af[2], bf[8];
        #pragma unroll
        for (int i = 0; i < 2; ++i)
            af[i] = *(const hfrag*)(As + (i*16 + frl)*32 + fq);
        #pragma unroll
        for (int j = 0; j < 8; ++j)
            bf[j] = *(const hfrag*)(Bs + (wave*128 + j*16 + frl)*32 + fq);
        #pragma unroll
        for (int i = 0; i < 2; ++i)
            #pragma unroll
            for (int j = 0; j < 8; ++j)
                acc[i][j] = __builtin_amdgcn_mfma_f32_16x16x32_f16(af[i], bf[j], acc[i][j], 0, 0, 0);
        __syncthreads();
    }
    // ---- phase 1: attn_pooled into LDS (overlay Bs; all waves past last read)
    float* ap_s = (float*)Bs;                    // [8][512]
    const int bl0 = m0 >> 2;
    const int b = bl0 >> 10;                     // 8 bls never straddle a batch
    float nv[KK];
    nsw_compute(sw, pres, b, nv);
    #pragma unroll
    for (int i = 0; i < 2; ++i) {
        int bl_loc = i*4 + q;
        int blg = bl0 + bl_loc;
        float s4[KK]; float ssum = 0.f;
        #pragma unroll
        for (int k = 0; k < KK; ++k) { s4[k] = nv[k] * rmask[blg*4 + k]; ssum += s4[k]; }
        float inv = 1.f / fmaxf(ssum, EPSF);
        #pragma unroll
        for (int j = 0; j < 8; ++j) {
            float ap = 0.f;
            #pragma unroll
            for (int r = 0; r < KK; ++r) ap = fmaf(s4[r]*inv, acc[i][j][r], ap);
            ap_s[bl_loc*512 + wave*128 + j*16 + frl] = ap;
        }
    }
    __syncthreads();
    // ---- phase 2: LN1 over [ap|wm|mx] per bl; 32 threads x 16 cols per bl
    const int blq = tid >> 5;
    const int c0  = (tid & 31) * 16;
    const int blg = bl0 + blq;
    float4 ap4[4], wm4[4], mx4[4];
    #pragma unroll
    for (int v = 0; v < 4; ++v) {
        ap4[v] = *(const float4*)(ap_s + blq*512 + c0 + v*4);
        wm4[v] = *(const float4*)(in_wm + (size_t)blg*512 + c0 + v*4);
        mx4[v] = *(const float4*)(in_mx + (size_t)blg*512 + c0 + v*4);
    }
    float s = 0.f, s2 = 0.f;
    #pragma unroll
    for (int c = 0; c < 16; ++c) {
        float ap = ((const float*)ap4)[c];
        float wm = ((const float*)wm4)[c];
        float mx = ((const float*)mx4)[c];
        s += ap + wm + mx; s2 += ap*ap + wm*wm + mx*mx;
    }
    #pragma unroll
    for (int o = 1; o < 32; o <<= 1) {
        s  += __shfl_xor(s,  o, 32);
        s2 += __shfl_xor(s2, o, 32);
    }
    float mu = s * (1.f/(float)D3);
    float var = s2 * (1.f/(float)D3) - mu*mu;
    float rstd = rsqrtf(var + LN_EPSF);
    #pragma unroll
    for (int v = 0; v < 4; ++v)
        *(float4*)(out_ap + (size_t)blg*512 + c0 + v*4) = ap4[v];
    #pragma unroll
    for (int seg = 0; seg < 3; ++seg) {
        const float* src = (seg == 0) ? (const float*)ap4
                         : (seg == 1) ? (const float*)wm4 : (const float*)mx4;
        int gofs = seg*512 + c0;
        #pragma unroll
        for (int v = 0; v < 4; ++v) {
            float4 g4 = *(const float4*)(ln1_g + gofs + v*4);
            float4 b4 = *(const float4*)(ln1_b + gofs + v*4);
            ushort4 o;
            o.x = f2h((src[v*4+0]-mu)*rstd*g4.x + b4.x);
            o.y = f2h((src[v*4+1]-mu)*rstd*g4.y + b4.y);
            o.z = f2h((src[v*4+2]-mu)*rstd*g4.z + b4.z);
            o.w = f2h((src[v*4+3]-mu)*rstd*g4.w + b4.w);
            *(ushort4*)(hin + (size_t)blg*D3 + gofs + v*4) = o;
        }
    }
}

// ---------------------------------------------------------------------------
// Fused Wg2 + sigmoid gate + fusion + final LN.  Per block 16 rows (bl) x all
// 512 cols; per-row LN via in-register fr-butterfly + tiny LDS cross-wave.
__global__ __launch_bounds__(256) void wg2_final_kernel(
        const unsigned short* __restrict__ A,   // gelu(h) (BL,512) fp16
        const unsigned short* __restrict__ W,   // Wg2 (512,512) fp16
        const float* __restrict__ bg2,
        const float* __restrict__ in_ap, const float* __restrict__ in_wm,
        const float* __restrict__ in_mx,
        const float* __restrict__ norm_g, const float* __restrict__ norm_b,
        float* __restrict__ fused) {
    __shared__ __align__(16) unsigned short As[16*32];
    __shared__ __align__(16) unsigned short Bs[512*32];
    __shared__ float rs[16*4], rq[16*4];
    const int tid = threadIdx.x, wave = tid >> 6, lane = tid & 63;
    const int m0 = blockIdx.x * 16;
    const int srow = lane >> 2, scol = (lane & 3) << 3;
    const unsigned short* Ag = A + (size_t)(m0 + srow)*512 + scol;
    unsigned short* Al = As + srow*32 + scol;
    const int brow = wave*128 + srow;
    const unsigned short* Wg = W + (size_t)brow*512 + scol;
    unsigned short* Blb = Bs + brow*32 + scol;
    const int q = lane >> 4, frl = lane & 15;
    const int fq = q * 8;
    f32x4 acc[8] = {};
    for (int k0 = 0; k0 < 512; k0 += 32) {
        if (wave == 0) glds16(Ag + k0, Al);
        #pragma unroll
        for (int i = 0; i < 8; ++i)
            glds16(Wg + (size_t)i*16*512 + k0, Blb + i*16*32);
        __syncthreads();
        hfrag af, bf[8];
        af = *(const hfrag*)(As + frl*32 + fq);
        #pragma unroll
        for (int j = 0; j < 8; ++j)
            bf[j] = *(const hfrag*)(Bs + (wave*128 + j*16 + frl)*32 + fq);
        #pragma unroll
        for (int j = 0; j < 8; ++j)
            acc[j] = __builtin_amdgcn_mfma_f32_16x16x32_f16(af, bf[j], acc[j], 0, 0, 0);
        __syncthreads();
    }
    // epilogue: rows = m0 + q*4 + r, cols = wave*128 + j*16 + frl
    float pre[8][4];
    float s[4] = {}, s2[4] = {};
    #pragma unroll
    for (int j = 0; j < 8; ++j) {
        int col = wave*128 + j*16 + frl;
        float bv = bg2[col];
        #pragma unroll
        for (int r = 0; r < 4; ++r) {
            int row = m0 + q*4 + r;
            float g = 1.f / (1.f + expf(-(acc[j][r] + bv)));
            float ap = in_ap[(size_t)row*512 + col];
            float wm = in_wm[(size_t)row*512 + col];
            float mx = in_mx[(size_t)row*512 + col];
            float p = g*0.5f*(ap + wm) + (1.f - g)*mx + wm;
            pre[j][r] = p;
            s[r] += p; s2[r] += p*p;
        }
    }
    #pragma unroll
    for (int r = 0; r < 4; ++r) {
        #pragma unroll
        for (int o = 1; o < 16; o <<= 1) {
            s[r]  += __shfl_xor(s[r],  o, 64);
            s2[r] += __shfl_xor(s2[r], o, 64);
        }
        if (frl == 0) {
            rs[(q*4+r)*4 + wave] = s[r];
            rq[(q*4+r)*4 + wave] = s2[r];
        }
    }
    __syncthreads();
    float mu[4], rstd[4];
    #pragma unroll
    for (int r = 0; r < 4; ++r) {
        int rl = q*4 + r;
        float ts  = rs[rl*4] + rs[rl*4+1] + rs[rl*4+2] + rs[rl*4+3];
        float tq  = rq[rl*4] + rq[rl*4+1] + rq[rl*4+2] + rq[rl*4+3];
        float m = ts * (1.f/(float)DD);
        float v = tq * (1.f/(float)DD) - m*m;
        mu[r] = m; rstd[r] = rsqrtf(v + LN_EPSF);
    }
    #pragma unroll
    for (int j = 0; j < 8; ++j) {
        int col = wave*128 + j*16 + frl;
        float g = norm_g[col], bb = norm_b[col];
        #pragma unroll
        for (int r = 0; r < 4; ++r) {
            int row = m0 + q*4 + r;
            fused[(size_t)row*512 + col] = (pre[j][r]-mu[r])*rstd[r]*g + bb;
        }
    }
}

// ---------------------------------------------------------------------------
// Per-(b,l) attention over K=4 states, fp16 q/k/v, fp32 math in LDS.
__global__ __launch_bounds__(256) void attn_kernel(
        unsigned short* Qb /* in: q, out: attn_out */,
        const unsigned short* __restrict__ Kb, const unsigned short* __restrict__ Vb,
        const float* __restrict__ sw, const int* __restrict__ pres,
        const float* __restrict__ rowmask,
        float* __restrict__ attn_mean_out) {
    __shared__ float qs[KK][DD];
    __shared__ float ksm[KK][DD];
    __shared__ float vs[KK][DD];
    __shared__ float att[128];           // [h*16 + i*4 + j]
    __shared__ float lw[KK], mk[KK];
    int bl = blockIdx.x, b = bl >> 10, mb = bl * KK;
    int tid = threadIdx.x;
    const ushort4* q4 = (const ushort4*)(Qb + (size_t)mb*DD);
    const ushort4* k4 = (const ushort4*)(Kb + (size_t)mb*DD);
    const ushort4* v4 = (const ushort4*)(Vb + (size_t)mb*DD);
    #pragma unroll
    for (int p = 0; p < 2; ++p) {
        int idx = p*256 + tid;
        int k = idx >> 7, dd = (idx & 127) << 2;
        ushort4 a = q4[idx];
        qs[k][dd] = h2f(a.x); qs[k][dd+1] = h2f(a.y); qs[k][dd+2] = h2f(a.z); qs[k][dd+3] = h2f(a.w);
        ushort4 c = k4[idx];
        ksm[k][dd] = h2f(c.x); ksm[k][dd+1] = h2f(c.y); ksm[k][dd+2] = h2f(c.z); ksm[k][dd+3] = h2f(c.w);
        ushort4 e = v4[idx];
        vs[k][dd] = h2f(e.x); vs[k][dd+1] = h2f(e.y); vs[k][dd+2] = h2f(e.z); vs[k][dd+3] = h2f(e.w);
    }
    if (tid < KK) {
        float nv[KK];
        nsw_compute(sw, pres, b, nv);
        lw[tid] = logf(fmaxf(nv[tid], EPSF));
        mk[tid] = rowmask[mb + tid];
    }
    __syncthreads();
    if (tid < 128) {
        int h = tid >> 4, i = (tid >> 2) & 3, j = tid & 3;
        float s = 0.f;
        #pragma unroll 16
        for (int d = 0; d < HD; ++d) s = fmaf(qs[i][h*HD + d], ksm[j][h*HD + d], s);
        float lg = s * SCALE + lw[j];
        att[tid] = (mk[j] > 0.5f) ? lg : -INFINITY;
    }
    __syncthreads();
    if (tid < 32) {
        int base = tid * 4;
        float l0 = att[base], l1 = att[base+1], l2 = att[base+2], l3 = att[base+3];
        float m = fmaxf(fmaxf(l0, l1), fmaxf(l2, l3));
        if (m == -INFINITY) {
            att[base] = att[base+1] = att[base+2] = att[base+3] = 0.f;
        } else {
            float e0 = expf(l0 - m), e1 = expf(l1 - m), e2 = expf(l2 - m), e3 = expf(l3 - m);
            float inv = 1.f / (e0 + e1 + e2 + e3);
            att[base] = e0*inv; att[base+1] = e1*inv; att[base+2] = e2*inv; att[base+3] = e3*inv;
        }
    }
    __syncthreads();
    if (tid < KK) {
        float s = 0.f;
        for (int hi = 0; hi < 32; ++hi) s += att[hi*4 + tid];
        attn_mean_out[(size_t)bl*KK + tid] = s * (1.f/32.f);
    }
    float outv[8];
    #pragma unroll
    for (int p = 0; p < 8; ++p) {
        int idx = p*256 + tid;
        int i = idx >> 9, dc = idx & 511, h = dc >> 6;
        float s = 0.f;
        #pragma unroll
        for (int j = 0; j < KK; ++j) s = fmaf(att[h*16 + i*4 + j], vs[j][dc], s);
        outv[p] = s;
    }
    #pragma unroll
    for (int p = 0; p < 8; ++p) {
        int idx = p*256 + tid;
        int i = idx >> 9, dc = idx & 511;
        Qb[(size_t)(mb+i)*DD + dc] = f2h(outv[p]);
    }
}

// ---------------------------------------------------------------------------
extern "C" void kernel_launch(void* const* d_in, const int* in_sizes, int n_in,
                              void* d_out, int out_size, void* d_ws, size_t ws_size,
                              hipStream_t stream) {
    const float* SR      = (const float*)d_in[0];
    const int*   residue = (const int*)d_in[1];
    const float* sw      = (const float*)d_in[2];
    const int*   roles   = (const int*)d_in[3];
    const int*   pres    = (const int*)d_in[4];
    const float* role_emb= (const float*)d_in[5];
    const float* Wq      = (const float*)d_in[6];
    const float* Wk      = (const float*)d_in[7];
    const float* Wv      = (const float*)d_in[8];
    const float* Wo      = (const float*)d_in[9];
    const float* ln1_g   = (const float*)d_in[10];
    const float* ln1_b   = (const float*)d_in[11];
    const float* Wg1     = (const float*)d_in[12];
    const float* bg1     = (const float*)d_in[13];
    const float* Wg2     = (const float*)d_in[14];
    const float* bg2     = (const float*)d_in[15];
    const float* norm_g  = (const float*)d_in[16];
    const float* norm_b  = (const float*)d_in[17];

    float* out = (float*)d_out;
    const size_t BLD = (size_t)BL * DD;
    float* f_fused = out;
    float* f_ap    = out + BLD;
    float* f_wm    = out + 2*BLD;
    float* f_mx    = out + 3*BLD;
    float* f_am    = out + 4*BLD;
    float* f_nsw   = out + 4*BLD + (size_t)BL*KK;

    char* base = (char*)d_ws;
    const size_t MD2 = (size_t)MM * DD * 2;     // 32 MB per fp16 activation buffer
    unsigned short* Xh = (unsigned short*)(base);
    unsigned short* Qh = (unsigned short*)(base + MD2);       // Q|K|V contiguous:
    unsigned short* Kh = (unsigned short*)(base + 2*MD2);     //  QKV routing relies
    unsigned short* Vh = (unsigned short*)(base + 3*MD2);     //  on this layout
    unsigned short* Wb = (unsigned short*)(base + 4*MD2);     // 4 MB weights
    float* rmask = (float*)(base + 4*MD2 + (size_t)WTOT*2);
    unsigned short* AOh  = Qh;   // attn_out (in-place over q)
    unsigned short* Hin  = Vh;   // (B,L,1536) fp16 (V dead after attn)
    unsigned short* Hbuf = Xh;   // gelu(h) (B,L,512) fp16 (X dead after QKV)
    const unsigned short* Wqkv = Wb;            // (1536, 512) = [Wq;Wk;Wv]
    const unsigned short* Woh  = Wb + 3*WSZ;
    const unsigned short* Wg1h = Wb + OG1;
    const unsigned short* Wg2h = Wb + OG2;

    dim3 blk(256);

    cvt_weights<<<WTOT/1024, blk, 0, stream>>>(Wq, Wk, Wv, Wo, Wg1, Wg2, Wb);
    buildx_kernel<<<(BL*128)/256, blk, 0, stream>>>(SR, residue, pres, roles, role_emb,
                                                    sw, Xh, rmask, f_wm, f_mx, f_nsw);

    // Fused QKV, XCD-swizzled flat grid (3072 blocks).
    gemm_mfma<128,0,1,1,1><<<dim3(3072), blk, 0, stream>>>(
        Xh, Wqkv, Qh, MM, 1536, DD, nullptr, nullptr);

    attn_kernel<<<BL, blk, 0, stream>>>(Qh, Kh, Vh, sw, pres, rmask, f_am);

    // Wo + pooling + LN1 fused: grid 1024 (4 blocks/CU).
    wo_pool_kernel<<<dim3(MM/32), blk, 0, stream>>>(
        AOh, Woh, sw, pres, rmask, f_wm, f_mx, ln1_g, ln1_b, f_ap, Hin);

    // Wg1 + GELU: TM=32 tiles.
    gemm_mfma<32,2,1,0,0><<<dim3(4, BL/32), blk, 0, stream>>>(
        Hin, Wg1h, Hbuf, BL, DD, D3, bg1, nullptr);

    // Wg2 + gate + fusion + final LN fused: grid 512.
    wg2_final_kernel<<<dim3(BL/16), blk, 0, stream>>>(
        Hbuf, Wg2h, bg2, f_ap, f_wm, f_mx, norm_g, norm_b, f_fused);
}